// Round 8
// baseline (215.151 us; speedup 1.0000x reference)
//
#include <hip/hip_runtime.h>
#include <hip/hip_bf16.h>

typedef __attribute__((ext_vector_type(8))) short short8;
typedef __attribute__((ext_vector_type(8))) unsigned short ushort8;
typedef __attribute__((ext_vector_type(4))) float f32x4;

#define LIN  8192
#define L3V  8189
#define NOUT 128
#define KP   8192
#define BM   64
#define BKX  256             // x-chunk width (1KB/row contiguous runs)
#define BKW  128             // W-tile width
#define NTX  (KP / BKX)      // 32 x-chunks
#define NTW  (KP / BKW)      // 64 W-tiles (= sub-chunks, 1 barrier each)
#define PITCHX (BKX + 8)     // 264 shorts/row
#define PITCHW (BKW + 8)     // 136 shorts/row

// round-to-nearest-even fp32 -> bf16 (values are finite here)
static __device__ __forceinline__ unsigned short f2bf(float f) {
    union { float f; unsigned u; } c; c.f = f;
    unsigned r = c.u + 0x7FFFu + ((c.u >> 16) & 1u);
    return (unsigned short)(r >> 16);
}

// W [128][8189] fp32 -> Wb [128][8192] bf16, zero-padded tail
__global__ void wprep(const float* __restrict__ W, unsigned short* __restrict__ Wb) {
    int idx = blockIdx.x * 256 + threadIdx.x;     // 0 .. 128*8192-1
    int n = idx >> 13;
    int k = idx & (KP - 1);
    float v = (k < L3V) ? W[(size_t)n * L3V + k] : 0.0f;
    Wb[idx] = f2bf(v);
}

__global__ __launch_bounds__(512, 2) void fused(
    const float* __restrict__ x,
    const float* __restrict__ w1, const float* __restrict__ b1,
    const float* __restrict__ w2, const float* __restrict__ b2,
    const float* __restrict__ w3, const float* __restrict__ b3,
    const unsigned short* __restrict__ Wb,
    const float* __restrict__ bias,
    float* __restrict__ out)
{
    __shared__ unsigned short hA[2][BM * PITCHX];     // 2 x 33792 B
    __shared__ unsigned short wA[2][NOUT * PITCHW];   // 2 x 34816 B  (total 137216 B)

    const int tid  = threadIdx.x;
    const int row0 = blockIdx.x * BM;

    const float w10 = w1[0], w11 = w1[1], cb1 = b1[0];
    const float w20 = w2[0], w21 = w2[1], cb2 = b2[0];
    const float w30 = w3[0], w31 = w3[1], cb3 = b3[0];

    // x staging: 64 rows x 8 segments of 32 h-values (1KB+halo per row per chunk)
    const int srow = tid >> 3;          // 0..63
    const int scol = (tid & 7) * 32;    // 0,32,...,224
    const float* xrow = x + (size_t)(row0 + srow) * LIN;

    // W staging: 128 rows x 4 quarters of 32 cols (per 128-wide W-tile)
    const int wn = tid >> 2;            // 0..127
    const int wq = tid & 3;             // 0..3
    const unsigned short* wrow = Wb + (size_t)wn * KP + wq * 32;

    // mfma mapping: 8 waves = 4 row-groups x 2 col-groups; wave = 16 rows x 64 cols
    const int lane = tid & 63;
    const int wid  = tid >> 6;
    const int wr   = wid >> 1;          // 0..3
    const int wc   = wid & 1;           // 0..1
    const int l15  = lane & 15;
    const int koff = (lane >> 4) * 8;
    const int arow_off = (wr * 16 + l15) * PITCHX + koff;

    f32x4 acc[4];
    #pragma unroll
    for (int f = 0; f < 4; ++f) acc[f] = (f32x4){0.f, 0.f, 0.f, 0.f};

    // single register staging set (R2 discipline: consume-then-reload)
    float   xv[36];
    ushort8 wv[4];

    auto load_x = [&](int t) {                    // t in [0, NTX)
        const int gk = t * BKX + scol;
        if (gk + 36 <= LIN) {                     // false only for t==31 && scol==224
            #pragma unroll
            for (int q = 0; q < 9; ++q) {
                const float4 v = *reinterpret_cast<const float4*>(xrow + gk + q * 4);
                xv[q*4+0] = v.x; xv[q*4+1] = v.y; xv[q*4+2] = v.z; xv[q*4+3] = v.w;
            }
        } else {
            #pragma unroll
            for (int q = 0; q < 8; ++q) {         // gk+32 == LIN here, in bounds
                const float4 v = *reinterpret_cast<const float4*>(xrow + gk + q * 4);
                xv[q*4+0] = v.x; xv[q*4+1] = v.y; xv[q*4+2] = v.z; xv[q*4+3] = v.w;
            }
            xv[32] = 0.f; xv[33] = 0.f; xv[34] = 0.f; xv[35] = 0.f;
            // affected h3 indices are >= L3V and get zero-masked in store_h
        }
    };

    auto load_w = [&](int wt) {                   // wt in [0, NTW)
        const ushort8* wsrc = reinterpret_cast<const ushort8*>(wrow + wt * BKW);
        #pragma unroll
        for (int i = 0; i < 4; ++i) wv[i] = wsrc[i];
    };

    auto store_w = [&](int ws) {
        ushort8* wdst = reinterpret_cast<ushort8*>(&wA[ws][wn * PITCHW + wq * 32]);
        #pragma unroll
        for (int i = 0; i < 4; ++i) wdst[i] = wv[i];
    };

    auto store_h = [&](int t, int hs) {
        const int gk = t * BKX + scol;
        float h1[34];
        #pragma unroll
        for (int j = 0; j < 34; ++j)
            h1[j] = fmaxf(fmaf(w10, xv[j], fmaf(w11, xv[j+1], cb1)), 0.0f);
        float h2[33];
        #pragma unroll
        for (int j = 0; j < 33; ++j)
            h2[j] = fmaxf(fmaf(w20, h1[j], fmaf(w21, h1[j+1], cb2)), 0.0f);
        ushort8 hp[4];
        #pragma unroll
        for (int j = 0; j < 32; ++j) {
            float h3 = fmaxf(fmaf(w30, h2[j], fmaf(w31, h2[j+1], cb3)), 0.0f);
            hp[j >> 3][j & 7] = (gk + j < L3V) ? f2bf(h3) : (unsigned short)0;
        }
        ushort8* hd = reinterpret_cast<ushort8*>(&hA[hs][srow * PITCHX + scol]);
        #pragma unroll
        for (int i = 0; i < 4; ++i) hd[i] = hp[i];
    };

    // mfma over one 128-wide k-half u of x-chunk in hA[hs], W-tile in wA[ws]
    auto mfma_half = [&](int hs, int u, int ws) {
        const unsigned short* hB = hA[hs];
        const unsigned short* wB = wA[ws];
        #pragma unroll
        for (int kk = 0; kk < BKW; kk += 32) {
            const short8 af = *reinterpret_cast<const short8*>(&hB[arow_off + u * BKW + kk]);
            #pragma unroll
            for (int f = 0; f < 4; ++f) {
                const int bn = wc * 64 + f * 16 + l15;
                const short8 bf = *reinterpret_cast<const short8*>(&wB[bn * PITCHW + kk + koff]);
                acc[f] = __builtin_amdgcn_mfma_f32_16x16x32_bf16(af, bf, acc[f], 0, 0, 0);
            }
        }
    };

    // prologue: wA[0] <- tile0, wv <- tile1; hA[0] <- chunk0, xv <- chunk1
    load_w(0);
    store_w(0);
    load_w(1);
    load_x(0);
    store_h(0, 0);
    load_x(1);
    __syncthreads();

    #pragma unroll 1
    for (int s = 0; s < NTW; ++s) {
        const int t  = s >> 1;          // x-chunk
        const int u  = s & 1;           // k-half within x-chunk
        const int hs = t & 1;
        const int ws = s & 1;
        mfma_half(hs, u, ws);                         // R2 order: compute first
        if (s + 1 < NTW) store_w((s + 1) & 1);        // wv(tile s+1) -> LDS
        if (u == 1 && t + 1 < NTX) store_h(t + 1, (t + 1) & 1);   // conv -> LDS
        if (s + 2 < NTW) load_w(s + 2);               // refill wv, stays in flight
        if (u == 1 && t + 2 < NTX) load_x(t + 2);     // refill xv, stays in flight
        __syncthreads();
    }

    // epilogue: C[m][n]: col = lane&15, row = (lane>>4)*4 + j   [m89 layout]
    #pragma unroll
    for (int f = 0; f < 4; ++f) {
        const int col = wc * 64 + f * 16 + l15;
        const float bv = bias[col];
        #pragma unroll
        for (int j = 0; j < 4; ++j) {
            const int grow = row0 + wr * 16 + (lane >> 4) * 4 + j;
            out[(size_t)grow * NOUT + col] = acc[f][j] + bv;
        }
    }
}

extern "C" void kernel_launch(void* const* d_in, const int* in_sizes, int n_in,
                              void* d_out, int out_size, void* d_ws, size_t ws_size,
                              hipStream_t stream) {
    const float* x  = (const float*)d_in[0];
    const float* w1 = (const float*)d_in[1];
    const float* b1 = (const float*)d_in[2];
    const float* w2 = (const float*)d_in[3];
    const float* b2 = (const float*)d_in[4];
    const float* w3 = (const float*)d_in[5];
    const float* b3 = (const float*)d_in[6];
    const float* W  = (const float*)d_in[7];
    const float* b  = (const float*)d_in[8];
    float* out = (float*)d_out;
    unsigned short* Wb = (unsigned short*)d_ws;   // 128*8192 bf16 = 2 MiB

    wprep<<<dim3((NOUT * KP) / 256), dim3(256), 0, stream>>>(W, Wb);
    fused<<<dim3(16384 / BM), dim3(512), 0, stream>>>(
        x, w1, b1, w2, b2, w3, b3, Wb, b, out);
}

// Round 9
// 181.634 us; speedup vs baseline: 1.1845x; 1.1845x over previous
//
#include <hip/hip_runtime.h>
#include <hip/hip_bf16.h>

typedef __attribute__((ext_vector_type(8))) short short8;
typedef __attribute__((ext_vector_type(8))) unsigned short ushort8;
typedef __attribute__((ext_vector_type(4))) float f32x4;

#define LIN  8192
#define L3V  8189
#define NOUT 128
#define KP   8192
#define BM   64
#define BK   128
#define NT   (KP / BK)       // 64 chunks
#define PITCH (BK + 8)       // 136 shorts/row

// round-to-nearest-even fp32 -> bf16 (values are finite here)
static __device__ __forceinline__ unsigned short f2bf(float f) {
    union { float f; unsigned u; } c; c.f = f;
    unsigned r = c.u + 0x7FFFu + ((c.u >> 16) & 1u);
    return (unsigned short)(r >> 16);
}

// W [128][8189] fp32 -> Wb in MFMA-fragment-major order, bf16, zero-padded.
// granule = one 16x32 B-subtile = 64 lanes x 8 bf16; lane l holds
// col-row (l&15), k-sub (l>>4)*8. Order: chunk t (64) -> col-group g (8) ->
// k-slice s (4) -> lane (64). 2048 granules = 2 MiB.  (verified in R5)
__global__ void wprep(const float* __restrict__ W, unsigned short* __restrict__ Wb) {
    int idx = blockIdx.x * 256 + threadIdx.x;     // granule*64 + lane, 0..131071
    const int lane = idx & 63;
    const int s    = (idx >> 6) & 3;
    const int g    = (idx >> 8) & 7;
    const int t    = idx >> 11;
    const int row  = g * 16 + (lane & 15);
    const int k0   = t * BK + s * 32 + (lane >> 4) * 8;
    ushort8 v;
    #pragma unroll
    for (int j = 0; j < 8; ++j) {
        const int k = k0 + j;
        v[j] = (k < L3V) ? f2bf(W[(size_t)row * L3V + k]) : (unsigned short)0;
    }
    *reinterpret_cast<ushort8*>(Wb + (size_t)idx * 8) = v;
}

__global__ __launch_bounds__(512, 2) void fused(
    const float* __restrict__ x,
    const float* __restrict__ w1, const float* __restrict__ b1,
    const float* __restrict__ w2, const float* __restrict__ b2,
    const float* __restrict__ w3, const float* __restrict__ b3,
    const unsigned short* __restrict__ Wb,
    const float* __restrict__ bias,
    float* __restrict__ out)
{
    __shared__ unsigned short hA[2][BM * PITCH];      // h only: 34816 B total

    const int tid  = threadIdx.x;
    const int row0 = blockIdx.x * BM;

    const float w10 = w1[0], w11 = w1[1], cb1 = b1[0];
    const float w20 = w2[0], w21 = w2[1], cb2 = b2[0];
    const float w30 = w3[0], w31 = w3[1], cb3 = b3[0];

    // x staging: 64 rows x 8 segments of 16 h-values (R2 mapping)
    const int srow = tid >> 3;          // 0..63
    const int scol = (tid & 7) * 16;    // 0,16,...,112
    const float* xrow = x + (size_t)(row0 + srow) * LIN;

    // mfma mapping: 8 waves = 2 row-groups x 4 col-groups; wave = 32 rows x 32 cols
    const int lane = tid & 63;
    const int wid  = tid >> 6;
    const int wr   = wid >> 2;          // 0..1
    const int wc   = wid & 3;           // 0..3
    const int l15  = lane & 15;
    const int koff = (lane >> 4) * 8;
    const int arow0 = (wr * 32 + l15) * PITCH + koff;
    const int arow1 = arow0 + 16 * PITCH;
    const int lane8 = lane * 8;
    const int wg2   = wc * 2;           // first 16-col-group this wave covers

    f32x4 acc[2][2];
    #pragma unroll
    for (int m = 0; m < 2; ++m)
        #pragma unroll
        for (int f = 0; f < 2; ++f) acc[m][f] = (f32x4){0.f, 0.f, 0.f, 0.f};

    // register staging (single sets, R2 discipline)
    float  xv[20];
    short8 wf[8];                       // B-fragments for current chunk: [s][f]

    auto stage_load = [&](int t) {
        const int gk = t * BK + scol;
        if (gk + 20 <= LIN) {                 // false only for t==NT-1 && scol==112
            #pragma unroll
            for (int q = 0; q < 5; ++q) {
                const float4 v = *reinterpret_cast<const float4*>(xrow + gk + q * 4);
                xv[q*4+0] = v.x; xv[q*4+1] = v.y; xv[q*4+2] = v.z; xv[q*4+3] = v.w;
            }
        } else {
            #pragma unroll
            for (int q = 0; q < 4; ++q) {     // gk+16 == LIN here, in bounds
                const float4 v = *reinterpret_cast<const float4*>(xrow + gk + q * 4);
                xv[q*4+0] = v.x; xv[q*4+1] = v.y; xv[q*4+2] = v.z; xv[q*4+3] = v.w;
            }
            xv[16] = 0.f; xv[17] = 0.f; xv[18] = 0.f; xv[19] = 0.f;
        }
    };

    // load the 8 B-fragments (chunk t) straight from fragment-major Wb (L2)
    auto wfrag_load = [&](int t) {
        #pragma unroll
        for (int s = 0; s < 4; ++s) {
            #pragma unroll
            for (int f = 0; f < 2; ++f) {
                const size_t goff = ((size_t)((t * 8 + wg2 + f) * 4 + s) << 9) + lane8;
                wf[s * 2 + f] = *reinterpret_cast<const short8*>(Wb + goff);
            }
        }
    };

    auto stage_store = [&](int t, int s) {
        const int gk = t * BK + scol;
        float h1[18];
        #pragma unroll
        for (int j = 0; j < 18; ++j)
            h1[j] = fmaxf(fmaf(w10, xv[j], fmaf(w11, xv[j+1], cb1)), 0.0f);
        float h2[17];
        #pragma unroll
        for (int j = 0; j < 17; ++j)
            h2[j] = fmaxf(fmaf(w20, h1[j], fmaf(w21, h1[j+1], cb2)), 0.0f);
        ushort8 hp[2];
        #pragma unroll
        for (int j = 0; j < 16; ++j) {
            float h3 = fmaxf(fmaf(w30, h2[j], fmaf(w31, h2[j+1], cb3)), 0.0f);
            hp[j >> 3][j & 7] = (gk + j < L3V) ? f2bf(h3) : (unsigned short)0;
        }
        ushort8* hd = reinterpret_cast<ushort8*>(&hA[s][srow * PITCH + scol]);
        hd[0] = hp[0];
        hd[1] = hp[1];
    };

    auto mfma_tile = [&](int s) {
        const unsigned short* hB = hA[s];
        #pragma unroll
        for (int ks = 0; ks < 4; ++ks) {
            const short8 af0 = *reinterpret_cast<const short8*>(&hB[arow0 + ks * 32]);
            const short8 af1 = *reinterpret_cast<const short8*>(&hB[arow1 + ks * 32]);
            acc[0][0] = __builtin_amdgcn_mfma_f32_16x16x32_bf16(af0, wf[ks*2+0], acc[0][0], 0, 0, 0);
            acc[1][0] = __builtin_amdgcn_mfma_f32_16x16x32_bf16(af1, wf[ks*2+0], acc[1][0], 0, 0, 0);
            acc[0][1] = __builtin_amdgcn_mfma_f32_16x16x32_bf16(af0, wf[ks*2+1], acc[0][1], 0, 0, 0);
            acc[1][1] = __builtin_amdgcn_mfma_f32_16x16x32_bf16(af1, wf[ks*2+1], acc[1][1], 0, 0, 0);
        }
    };

    // prologue: hA[0] <- chunk0; xv <- chunk1; wf <- chunk0
    stage_load(0);
    stage_store(0, 0);
    stage_load(1);
    wfrag_load(0);
    __syncthreads();

    int sel = 0;
    #pragma unroll 1
    for (int t = 0; t < NT; ++t) {
        mfma_tile(sel);                               // consumes wf (chunk t)
        if (t + 1 < NT) wfrag_load(t + 1);            // refill wf from L2, long cover
        if (t + 1 < NT) stage_store(t + 1, sel ^ 1);  // conv xv -> LDS
        if (t + 2 < NT) stage_load(t + 2);            // refill xv, stays in flight
        __syncthreads();
        sel ^= 1;
    }

    // epilogue: C[m][n]: col = lane&15, row = (lane>>4)*4 + j   [m89 layout]
    #pragma unroll
    for (int m = 0; m < 2; ++m) {
        #pragma unroll
        for (int f = 0; f < 2; ++f) {
            const int col = wc * 32 + f * 16 + l15;
            const float bv = bias[col];
            #pragma unroll
            for (int j = 0; j < 4; ++j) {
                const int grow = row0 + wr * 32 + m * 16 + (lane >> 4) * 4 + j;
                out[(size_t)grow * NOUT + col] = acc[m][f][j] + bv;
            }
        }
    }
}

extern "C" void kernel_launch(void* const* d_in, const int* in_sizes, int n_in,
                              void* d_out, int out_size, void* d_ws, size_t ws_size,
                              hipStream_t stream) {
    const float* x  = (const float*)d_in[0];
    const float* w1 = (const float*)d_in[1];
    const float* b1 = (const float*)d_in[2];
    const float* w2 = (const float*)d_in[3];
    const float* b2 = (const float*)d_in[4];
    const float* w3 = (const float*)d_in[5];
    const float* b3 = (const float*)d_in[6];
    const float* W  = (const float*)d_in[7];
    const float* b  = (const float*)d_in[8];
    float* out = (float*)d_out;
    unsigned short* Wb = (unsigned short*)d_ws;   // 2 MiB, fragment-major

    wprep<<<dim3(512), dim3(256), 0, stream>>>(W, Wb);
    fused<<<dim3(16384 / BM), dim3(512), 0, stream>>>(
        x, w1, b1, w2, b2, w3, b3, Wb, b, out);
}